// Round 9
// baseline (236.968 us; speedup 1.0000x reference)
//
#include <hip/hip_runtime.h>
#include <hip/hip_bf16.h>
#include <cstdint>

#define NQ 4096
#define NK 4160        // 4096 pooled spatial + 64 ptr = 130 tiles of 32
#define NSP 16384
#define E 256
#define HD 32
// Q is pre-scaled by SC2E = SCALE*log2e at projection time, so p = exp2(S + c2)
#define SC2E 0.2550348652937f
#define C2_SP  -12.426950408889634f   // (ln4 - 10) * log2e
#define C2_PTR -14.426950408889634f   // (-10) * log2e

typedef __attribute__((ext_vector_type(4))) float f32x4;
typedef __attribute__((ext_vector_type(8))) __bf16 bf16x8;
typedef __attribute__((ext_vector_type(4))) __bf16 bf16x4;

// ============ weights prep: W^T hi/lo (4 x 256x256) ============
__global__ __launch_bounds__(256) void wprep_kernel(
    const float* __restrict__ Wq, const float* __restrict__ Wk,
    const float* __restrict__ Wv, const float* __restrict__ Wo,
    __bf16* __restrict__ wthi, __bf16* __restrict__ wtlo)
{
  __shared__ float tl[32][33];
  const int b = blockIdx.x, t = threadIdx.x;
  const int wsel = b >> 6, tile = b & 63;
  const float* W = (wsel == 0) ? Wq : (wsel == 1) ? Wk : (wsel == 2) ? Wv : Wo;
  __bf16* oh = wthi + (size_t)wsel * 65536;
  __bf16* ol = wtlo + (size_t)wsel * 65536;
  const int tr = (tile >> 3) * 32, tc = (tile & 7) * 32;
  const int rr = t >> 3, cc = (t & 7) * 4;
  *(float4*)&tl[rr][cc] = *(const float4*)(W + (size_t)(tr + rr) * E + tc + cc);
  __syncthreads();
  bf16x4 hv, lv;
#pragma unroll
  for (int i = 0; i < 4; ++i) {
    float x = tl[cc + i][rr];           // W[tr+cc+i][tc+rr]
    __bf16 bh = (__bf16)x;
    hv[i] = bh;
    lv[i] = (__bf16)(x - (float)bh);
  }
  *(bf16x4*)(oh + (size_t)(tc + rr) * E + tr + cc) = hv;
  *(bf16x4*)(ol + (size_t)(tc + rr) * E + tr + cc) = lv;
}

// ============ fused stage(+pool)+MFMA projection: 16 rows x 256 cols per block ============
// MODE 0: Q (f32 in) -> bf16 [h][n][32], scaled by SC2E
// MODE 1: K (f32 in, pooled) -> bf16 [h][n][32]
// MODE 2: V (f32 in, pooled) -> bf16 V^T permuted [h*32+d][NK] (swapped operands)
template<int MODE>
__device__ __forceinline__ void qkv_body(
    const float* __restrict__ Xsrc, const __bf16* __restrict__ WTH,
    const float* __restrict__ bias, void* __restrict__ Y, int r0)
{
  __shared__ __bf16 Xs[16][264];   // pad 264: <=2-way banks on b128 frag reads
  const int t = threadIdx.x;

  // ---- stage: pool (K/V) or copy (Q), f32 -> bf16, into LDS ----
  {
    const int pr = t >> 4, f4 = t & 15;   // pooled row, float4-chunk
    const int p = r0 + pr;
    float4 x[4];
    if (MODE == 0) {
      const float* src = Xsrc + (size_t)p * E + f4 * 4;
#pragma unroll
      for (int j = 0; j < 4; ++j) x[j] = *(const float4*)(src + j * 64);
    } else if (p < 4096) {
      const int fr = p >> 10, hp = (p >> 5) & 31, wp = p & 31;
      const float* src = Xsrc + (size_t)(fr * 4096 + hp * 128 + wp * 2) * E + f4 * 4;
#pragma unroll
      for (int j = 0; j < 4; ++j) {
        float4 a = *(const float4*)(src + j * 64);
        float4 b = *(const float4*)(src + j * 64 + E);
        float4 c = *(const float4*)(src + j * 64 + 64 * E);
        float4 d = *(const float4*)(src + j * 64 + 65 * E);
        x[j].x = 0.25f * (a.x + b.x + c.x + d.x);
        x[j].y = 0.25f * (a.y + b.y + c.y + d.y);
        x[j].z = 0.25f * (a.z + b.z + c.z + d.z);
        x[j].w = 0.25f * (a.w + b.w + c.w + d.w);
      }
    } else {
      const float* src = Xsrc + (size_t)(NSP + p - 4096) * E + f4 * 4;
#pragma unroll
      for (int j = 0; j < 4; ++j) x[j] = *(const float4*)(src + j * 64);
    }
#pragma unroll
    for (int j = 0; j < 4; ++j) {
      bf16x4 o;
      o[0] = (__bf16)x[j].x; o[1] = (__bf16)x[j].y;
      o[2] = (__bf16)x[j].z; o[3] = (__bf16)x[j].w;
      *(bf16x4*)&Xs[pr][f4 * 4 + j * 64] = o;
    }
  }
  __syncthreads();

  // ---- compute ----
  const int lane = t & 63, ql = lane & 15, g = lane >> 4;
  const int w = t >> 6, c0 = w * 64;
  const __bf16* wh0 = WTH + (size_t)(c0 + ql) * E + g * 8;

  f32x4 acc[4] = {};
#pragma unroll
  for (int k0 = 0; k0 < 8; ++k0) {
    bf16x8 a = *(const bf16x8*)&Xs[ql][g * 8 + k0 * 32];
#pragma unroll
    for (int j = 0; j < 4; ++j) {
      bf16x8 bh = *(const bf16x8*)(wh0 + (size_t)j * 16 * E + k0 * 32);
      if (MODE == 2) acc[j] = __builtin_amdgcn_mfma_f32_16x16x32_bf16(bh, a, acc[j], 0, 0, 0);
      else           acc[j] = __builtin_amdgcn_mfma_f32_16x16x32_bf16(a, bh, acc[j], 0, 0, 0);
    }
  }

  if (MODE == 0 || MODE == 1) {
    const int NN = (MODE == 0) ? NQ : NK;
#pragma unroll
    for (int j = 0; j < 4; ++j) {
      const int c = c0 + 16 * j + ql;
      const float bv = bias[c];
      const int hh = c >> 5, d = c & 31;
      __bf16* dst = (__bf16*)Y + (size_t)hh * NN * HD + d;
#pragma unroll
      for (int r = 0; r < 4; ++r) {
        const int n = r0 + g * 4 + r;
        float o = acc[j][r] + bv;
        if (MODE == 0) o *= SC2E;
        dst[(size_t)n * HD] = (__bf16)o;
      }
    }
  } else {
    const int n = r0 + ql;
    const int wi = n & 31;
    const int pos = ((wi & 15) >> 2) * 8 + (wi & 3) + 4 * ((wi >> 4) & 1);
    const size_t nb = (size_t)(n >> 5) * 32 + pos;
#pragma unroll
    for (int j = 0; j < 4; ++j)
#pragma unroll
      for (int r = 0; r < 4; ++r) {
        const int ch = c0 + 16 * j + g * 4 + r;
        const int hh = ch >> 5, d = ch & 31;
        ((__bf16*)Y)[(size_t)(hh * HD + d) * NK + nb] = (__bf16)(acc[j][r] + bias[ch]);
      }
  }
}

// fused Q/K/V projection: blocks [0,256) Q, [256,516) K, [516,776) V
__global__ __launch_bounds__(256) void gemm_qkv(
    const float* __restrict__ q, const float* __restrict__ k, const float* __restrict__ v,
    const __bf16* __restrict__ wthi,
    const float* __restrict__ bq, const float* __restrict__ bk, const float* __restrict__ bv,
    __bf16* __restrict__ qb, __bf16* __restrict__ kb, __bf16* __restrict__ vtp)
{
  const int b = blockIdx.x;
  if (b < 256) {
    qkv_body<0>(q, wthi, bq, qb, b * 16);
  } else if (b < 516) {
    qkv_body<1>(k, wthi + 65536, bk, kb, (b - 256) * 16);
  } else {
    qkv_body<2>(v, wthi + 2 * 65536, bv, vtp, (b - 516) * 16);
  }
}

// ============ O-GEMM: out = [ahi+alo](N,256) @ Wo(256,256) + bo, 3-mfma hi/lo ============
__global__ __launch_bounds__(256) void gemm_o(
    const __bf16* __restrict__ ahi, const __bf16* __restrict__ alo,
    const __bf16* __restrict__ WTH, const __bf16* __restrict__ WTL,
    const float* __restrict__ bias, float* __restrict__ out)
{
  const int r0 = blockIdx.x * 16;
  const int t = threadIdx.x;
  const int lane = t & 63, ql = lane & 15, g = lane >> 4;
  const int w = t >> 6, c0 = w * 64;

  const __bf16* xp  = ahi + (size_t)(r0 + ql) * E + g * 8;
  const __bf16* xlp = alo + (size_t)(r0 + ql) * E + g * 8;
  const __bf16* wh0 = WTH + (size_t)(c0 + ql) * E + g * 8;
  const __bf16* wl0 = WTL + (size_t)(c0 + ql) * E + g * 8;

  f32x4 acc[4] = {};
#pragma unroll
  for (int k0 = 0; k0 < 8; ++k0) {
    bf16x8 a  = *(const bf16x8*)(xp + k0 * 32);
    bf16x8 al = *(const bf16x8*)(xlp + k0 * 32);
#pragma unroll
    for (int j = 0; j < 4; ++j) {
      bf16x8 bh = *(const bf16x8*)(wh0 + (size_t)j * 16 * E + k0 * 32);
      bf16x8 bl = *(const bf16x8*)(wl0 + (size_t)j * 16 * E + k0 * 32);
      acc[j] = __builtin_amdgcn_mfma_f32_16x16x32_bf16(a,  bh, acc[j], 0, 0, 0);
      acc[j] = __builtin_amdgcn_mfma_f32_16x16x32_bf16(al, bh, acc[j], 0, 0, 0);
      acc[j] = __builtin_amdgcn_mfma_f32_16x16x32_bf16(a,  bl, acc[j], 0, 0, 0);
    }
  }
#pragma unroll
  for (int j = 0; j < 4; ++j) {
    const int c = c0 + 16 * j + ql;
    const float bv = bias[c];
#pragma unroll
    for (int r = 0; r < 4; ++r) {
      const int n = r0 + g * 4 + r;
      out[(size_t)n * E + c] = acc[j][r] + bv;
    }
  }
}

// ============ no-LDS MFMA flash attention, 64q/wave, full-occupancy TLP ============
// grid 512 = 64 qtiles x 8 heads (h = blockIdx&7 -> per-XCD L2 K/V residency)
// block 1024 = 16 waves; wave w: 64 queries x key-tiles [st, st+nt) of 32 keys
// (tiles 9/9/8x14 = 130). 4 q-frags per wave, 1-deep register prefetch (the
// R7-proven loop). 512 blocks x 16 waves = 8192 waves = 32/CU (2 blocks/CU,
// LDS 75.8KB, VGPR capped 64 by launch_bounds) -> 8 waves/SIMD hide L2 latency.
__global__ __launch_bounds__(1024, 8) void attn_kernel(
    const __bf16* __restrict__ qb, const __bf16* __restrict__ kb,
    const __bf16* __restrict__ vtp, __bf16* __restrict__ ahi, __bf16* __restrict__ alo)
{
  __shared__ float OUT[8][64][36];   // pad 36: 16B-aligned f32x4, 2-way banks max
  __shared__ float LS[8][64];

  const int t = threadIdx.x;
  const int w = t >> 6, lane = t & 63;
  const int ql = lane & 15, g = lane >> 4;
  const int b = blockIdx.x;
  const int h = b & 7, qt = b >> 3;
  const int n0 = qt * 64;

  bf16x8 bq[4];
#pragma unroll
  for (int f = 0; f < 4; ++f)
    bq[f] = *(const bf16x8*)(qb + ((size_t)h * NQ + n0 + f * 16 + ql) * HD + g * 8);

  const int st = w * 8 + (w < 2 ? w : 2);   // 0,9,18,26,...,122
  const int nt = 8 + (w < 2 ? 1 : 0);       // 9,9,8x14 -> 130

  const __bf16* kp = kb  + ((size_t)h * NK + st * 32 + ql) * HD + g * 8;
  const __bf16* vp = vtp + ((size_t)(h * HD) + ql) * NK + st * 32 + g * 8;  // dims 0-15
  const __bf16* vq = vp + (size_t)16 * NK;                                  // dims 16-31

  f32x4 o0[4] = {}, o1[4] = {};
  float ls[4] = {0.f, 0.f, 0.f, 0.f};

  bf16x8 kf0 = *(const bf16x8*)(kp);
  bf16x8 kf1 = *(const bf16x8*)(kp + 512);
  bf16x8 vf0 = *(const bf16x8*)(vp);
  bf16x8 vf1 = *(const bf16x8*)(vq);

#define TILE(C2V)                                                                   \
  _Pragma("unroll")                                                                 \
  for (int f = 0; f < 4; ++f) {                                                     \
    f32x4 s0 = __builtin_amdgcn_mfma_f32_16x16x32_bf16(kf0, bq[f], C2V, 0, 0, 0);   \
    f32x4 s1 = __builtin_amdgcn_mfma_f32_16x16x32_bf16(kf1, bq[f], C2V, 0, 0, 0);   \
    float e0 = __builtin_amdgcn_exp2f(s0[0]), e1 = __builtin_amdgcn_exp2f(s0[1]);   \
    float e2 = __builtin_amdgcn_exp2f(s0[2]), e3 = __builtin_amdgcn_exp2f(s0[3]);   \
    float e4 = __builtin_amdgcn_exp2f(s1[0]), e5 = __builtin_amdgcn_exp2f(s1[1]);   \
    float e6 = __builtin_amdgcn_exp2f(s1[2]), e7 = __builtin_amdgcn_exp2f(s1[3]);   \
    ls[f] += ((e0 + e1) + (e2 + e3)) + ((e4 + e5) + (e6 + e7));                     \
    bf16x8 p;                                                                       \
    p[0] = (__bf16)e0; p[1] = (__bf16)e1; p[2] = (__bf16)e2; p[3] = (__bf16)e3;     \
    p[4] = (__bf16)e4; p[5] = (__bf16)e5; p[6] = (__bf16)e6; p[7] = (__bf16)e7;     \
    o0[f] = __builtin_amdgcn_mfma_f32_16x16x32_bf16(p, vf0, o0[f], 0, 0, 0);        \
    o1[f] = __builtin_amdgcn_mfma_f32_16x16x32_bf16(p, vf1, o1[f], 0, 0, 0);        \
  }

  for (int it = 0; it < nt - 1; ++it) {
    bf16x8 nk0 = *(const bf16x8*)(kp + (size_t)(it + 1) * 1024);
    bf16x8 nk1 = *(const bf16x8*)(kp + (size_t)(it + 1) * 1024 + 512);
    bf16x8 nv0 = *(const bf16x8*)(vp + (size_t)(it + 1) * 32);
    bf16x8 nv1 = *(const bf16x8*)(vq + (size_t)(it + 1) * 32);
    const float c2 = (st + it < 128) ? C2_SP : C2_PTR;
    const f32x4 c2v = {c2, c2, c2, c2};
    TILE(c2v)
    kf0 = nk0; kf1 = nk1; vf0 = nv0; vf1 = nv1;
  }
  {
    const float c2 = (st + nt - 1 < 128) ? C2_SP : C2_PTR;
    const f32x4 c2v = {c2, c2, c2, c2};
    TILE(c2v)
  }
#undef TILE

#pragma unroll
  for (int f = 0; f < 4; ++f) {
    ls[f] += __shfl_xor(ls[f], 16);
    ls[f] += __shfl_xor(ls[f], 32);
  }

  // two-phase partial merge: waves 0-7 write, waves 8-15 add
  if (w < 8) {
#pragma unroll
    for (int f = 0; f < 4; ++f) {
#pragma unroll
      for (int r = 0; r < 4; ++r) {
        OUT[w][f * 16 + g * 4 + r][ql]      = o0[f][r];
        OUT[w][f * 16 + g * 4 + r][16 + ql] = o1[f][r];
      }
      if (g == 0) LS[w][f * 16 + ql] = ls[f];
    }
  }
  __syncthreads();
  if (w >= 8) {
    const int w8 = w - 8;
#pragma unroll
    for (int f = 0; f < 4; ++f) {
#pragma unroll
      for (int r = 0; r < 4; ++r) {
        OUT[w8][f * 16 + g * 4 + r][ql]      += o0[f][r];
        OUT[w8][f * 16 + g * 4 + r][16 + ql] += o1[f][r];
      }
      if (g == 0) LS[w8][f * 16 + ql] += ls[f];
    }
  }
  __syncthreads();

  if (t < 512) {
    const int q = t >> 3, d0 = (t & 7) * 4;
    f32x4 s = *(const f32x4*)&OUT[0][q][d0];
    float lsum = LS[0][q];
#pragma unroll
    for (int w2 = 1; w2 < 8; ++w2) {
      s += *(const f32x4*)&OUT[w2][q][d0];
      lsum += LS[w2][q];
    }
    const float inv = 1.0f / lsum;
    bf16x4 hv, lv;
#pragma unroll
    for (int i = 0; i < 4; ++i) {
      float o = s[i] * inv;
      __bf16 bh = (__bf16)o;
      hv[i] = bh;
      lv[i] = (__bf16)(o - (float)bh);
    }
    const size_t off = (size_t)(n0 + q) * E + h * HD + d0;
    *(bf16x4*)(ahi + off) = hv;
    *(bf16x4*)(alo + off) = lv;
  }
}

extern "C" void kernel_launch(void* const* d_in, const int* in_sizes, int n_in,
                              void* d_out, int out_size, void* d_ws, size_t ws_size,
                              hipStream_t stream)
{
  const float* q  = (const float*)d_in[0];
  const float* k  = (const float*)d_in[1];
  const float* v  = (const float*)d_in[2];
  const float* Wq = (const float*)d_in[3];
  const float* bq = (const float*)d_in[4];
  const float* Wk = (const float*)d_in[5];
  const float* bk = (const float*)d_in[6];
  const float* Wv = (const float*)d_in[7];
  const float* bv = (const float*)d_in[8];
  const float* Wo = (const float*)d_in[9];
  const float* bo = (const float*)d_in[10];
  float* out = (float*)d_out;

  char* wsp = (char*)d_ws;
  __bf16* wthi = (__bf16*)(wsp);               //   524,288 (4 x 256x256)
  __bf16* wtlo = (__bf16*)(wsp + 524288);      //   524,288
  __bf16* qbb  = (__bf16*)(wsp + 1048576);     // 2,097,152
  __bf16* kbb  = (__bf16*)(wsp + 3145728);     // 2,129,920
  __bf16* vtp  = (__bf16*)(wsp + 5275648);     // 2,129,920
  __bf16* ahi  = (__bf16*)(wsp + 7405568);     // 2,097,152
  __bf16* alo  = (__bf16*)(wsp + 9502720);     // 2,097,152 -> end 11,599,872

  wprep_kernel<<<256, 256, 0, stream>>>(Wq, Wk, Wv, Wo, wthi, wtlo);
  gemm_qkv<<<776, 256, 0, stream>>>(q, k, v, wthi, bq, bk, bv, qbb, kbb, vtp);
  attn_kernel<<<512, 1024, 0, stream>>>(qbb, kbb, vtp, ahi, alo);
  gemm_o<<<256, 256, 0, stream>>>(ahi, alo, wthi + 3 * 65536, wtlo + 3 * 65536, bo, out);
}

// Round 10
// 96.510 us; speedup vs baseline: 2.4554x; 2.4554x over previous
//
#include <hip/hip_runtime.h>
#include <hip/hip_bf16.h>
#include <cstdint>

#define NQ 4096
#define NK 4160        // 4096 pooled spatial + 64 ptr = 130 tiles of 32
#define NSP 16384
#define E 256
#define HD 32
// Q is pre-scaled by SC2E = SCALE*log2e at projection time, so p = exp2(S + c2)
#define SC2E 0.2550348652937f
#define C2_SP  -12.426950408889634f   // (ln4 - 10) * log2e
#define C2_PTR -14.426950408889634f   // (-10) * log2e

typedef __attribute__((ext_vector_type(4))) float f32x4;
typedef __attribute__((ext_vector_type(8))) __bf16 bf16x8;
typedef __attribute__((ext_vector_type(4))) __bf16 bf16x4;

// ============ weights prep: W^T hi/lo (4 x 256x256) ============
__global__ __launch_bounds__(256) void wprep_kernel(
    const float* __restrict__ Wq, const float* __restrict__ Wk,
    const float* __restrict__ Wv, const float* __restrict__ Wo,
    __bf16* __restrict__ wthi, __bf16* __restrict__ wtlo)
{
  __shared__ float tl[32][33];
  const int b = blockIdx.x, t = threadIdx.x;
  const int wsel = b >> 6, tile = b & 63;
  const float* W = (wsel == 0) ? Wq : (wsel == 1) ? Wk : (wsel == 2) ? Wv : Wo;
  __bf16* oh = wthi + (size_t)wsel * 65536;
  __bf16* ol = wtlo + (size_t)wsel * 65536;
  const int tr = (tile >> 3) * 32, tc = (tile & 7) * 32;
  const int rr = t >> 3, cc = (t & 7) * 4;
  *(float4*)&tl[rr][cc] = *(const float4*)(W + (size_t)(tr + rr) * E + tc + cc);
  __syncthreads();
  bf16x4 hv, lv;
#pragma unroll
  for (int i = 0; i < 4; ++i) {
    float x = tl[cc + i][rr];           // W[tr+cc+i][tc+rr]
    __bf16 bh = (__bf16)x;
    hv[i] = bh;
    lv[i] = (__bf16)(x - (float)bh);
  }
  *(bf16x4*)(oh + (size_t)(tc + rr) * E + tr + cc) = hv;
  *(bf16x4*)(ol + (size_t)(tc + rr) * E + tr + cc) = lv;
}

// ============ fused stage(+pool)+MFMA projection: 16 rows x 256 cols per block ============
// MODE 0: Q (f32 in) -> bf16 [h][n][32], scaled by SC2E
// MODE 1: K (f32 in, pooled) -> bf16 [h][n][32]
// MODE 2: V (f32 in, pooled) -> bf16 V^T permuted [h*32+d][NK] (swapped operands)
template<int MODE>
__device__ __forceinline__ void qkv_body(
    const float* __restrict__ Xsrc, const __bf16* __restrict__ WTH,
    const float* __restrict__ bias, void* __restrict__ Y, int r0)
{
  __shared__ __bf16 Xs[16][264];   // pad 264: <=2-way banks on b128 frag reads
  const int t = threadIdx.x;

  // ---- stage: pool (K/V) or copy (Q), f32 -> bf16, into LDS ----
  {
    const int pr = t >> 4, f4 = t & 15;   // pooled row, float4-chunk
    const int p = r0 + pr;
    float4 x[4];
    if (MODE == 0) {
      const float* src = Xsrc + (size_t)p * E + f4 * 4;
#pragma unroll
      for (int j = 0; j < 4; ++j) x[j] = *(const float4*)(src + j * 64);
    } else if (p < 4096) {
      const int fr = p >> 10, hp = (p >> 5) & 31, wp = p & 31;
      const float* src = Xsrc + (size_t)(fr * 4096 + hp * 128 + wp * 2) * E + f4 * 4;
#pragma unroll
      for (int j = 0; j < 4; ++j) {
        float4 a = *(const float4*)(src + j * 64);
        float4 b = *(const float4*)(src + j * 64 + E);
        float4 c = *(const float4*)(src + j * 64 + 64 * E);
        float4 d = *(const float4*)(src + j * 64 + 65 * E);
        x[j].x = 0.25f * (a.x + b.x + c.x + d.x);
        x[j].y = 0.25f * (a.y + b.y + c.y + d.y);
        x[j].z = 0.25f * (a.z + b.z + c.z + d.z);
        x[j].w = 0.25f * (a.w + b.w + c.w + d.w);
      }
    } else {
      const float* src = Xsrc + (size_t)(NSP + p - 4096) * E + f4 * 4;
#pragma unroll
      for (int j = 0; j < 4; ++j) x[j] = *(const float4*)(src + j * 64);
    }
#pragma unroll
    for (int j = 0; j < 4; ++j) {
      bf16x4 o;
      o[0] = (__bf16)x[j].x; o[1] = (__bf16)x[j].y;
      o[2] = (__bf16)x[j].z; o[3] = (__bf16)x[j].w;
      *(bf16x4*)&Xs[pr][f4 * 4 + j * 64] = o;
    }
  }
  __syncthreads();

  // ---- compute ----
  const int lane = t & 63, ql = lane & 15, g = lane >> 4;
  const int w = t >> 6, c0 = w * 64;
  const __bf16* wh0 = WTH + (size_t)(c0 + ql) * E + g * 8;

  f32x4 acc[4] = {};
#pragma unroll
  for (int k0 = 0; k0 < 8; ++k0) {
    bf16x8 a = *(const bf16x8*)&Xs[ql][g * 8 + k0 * 32];
#pragma unroll
    for (int j = 0; j < 4; ++j) {
      bf16x8 bh = *(const bf16x8*)(wh0 + (size_t)j * 16 * E + k0 * 32);
      if (MODE == 2) acc[j] = __builtin_amdgcn_mfma_f32_16x16x32_bf16(bh, a, acc[j], 0, 0, 0);
      else           acc[j] = __builtin_amdgcn_mfma_f32_16x16x32_bf16(a, bh, acc[j], 0, 0, 0);
    }
  }

  if (MODE == 0 || MODE == 1) {
    const int NN = (MODE == 0) ? NQ : NK;
#pragma unroll
    for (int j = 0; j < 4; ++j) {
      const int c = c0 + 16 * j + ql;
      const float bv = bias[c];
      const int hh = c >> 5, d = c & 31;
      __bf16* dst = (__bf16*)Y + (size_t)hh * NN * HD + d;
#pragma unroll
      for (int r = 0; r < 4; ++r) {
        const int n = r0 + g * 4 + r;
        float o = acc[j][r] + bv;
        if (MODE == 0) o *= SC2E;
        dst[(size_t)n * HD] = (__bf16)o;
      }
    }
  } else {
    const int n = r0 + ql;
    const int wi = n & 31;
    const int pos = ((wi & 15) >> 2) * 8 + (wi & 3) + 4 * ((wi >> 4) & 1);
    const size_t nb = (size_t)(n >> 5) * 32 + pos;
#pragma unroll
    for (int j = 0; j < 4; ++j)
#pragma unroll
      for (int r = 0; r < 4; ++r) {
        const int ch = c0 + 16 * j + g * 4 + r;
        const int hh = ch >> 5, d = ch & 31;
        ((__bf16*)Y)[(size_t)(hh * HD + d) * NK + nb] = (__bf16)(acc[j][r] + bias[ch]);
      }
  }
}

// fused Q/K/V projection: blocks [0,256) Q, [256,516) K, [516,776) V
__global__ __launch_bounds__(256) void gemm_qkv(
    const float* __restrict__ q, const float* __restrict__ k, const float* __restrict__ v,
    const __bf16* __restrict__ wthi,
    const float* __restrict__ bq, const float* __restrict__ bk, const float* __restrict__ bv,
    __bf16* __restrict__ qb, __bf16* __restrict__ kb, __bf16* __restrict__ vtp)
{
  const int b = blockIdx.x;
  if (b < 256) {
    qkv_body<0>(q, wthi, bq, qb, b * 16);
  } else if (b < 516) {
    qkv_body<1>(k, wthi + 65536, bk, kb, (b - 256) * 16);
  } else {
    qkv_body<2>(v, wthi + 2 * 65536, bv, vtp, (b - 516) * 16);
  }
}

// ============ O-GEMM: out = [ahi+alo](N,256) @ Wo(256,256) + bo, 3-mfma hi/lo ============
__global__ __launch_bounds__(256) void gemm_o(
    const __bf16* __restrict__ ahi, const __bf16* __restrict__ alo,
    const __bf16* __restrict__ WTH, const __bf16* __restrict__ WTL,
    const float* __restrict__ bias, float* __restrict__ out)
{
  const int r0 = blockIdx.x * 16;
  const int t = threadIdx.x;
  const int lane = t & 63, ql = lane & 15, g = lane >> 4;
  const int w = t >> 6, c0 = w * 64;

  const __bf16* xp  = ahi + (size_t)(r0 + ql) * E + g * 8;
  const __bf16* xlp = alo + (size_t)(r0 + ql) * E + g * 8;
  const __bf16* wh0 = WTH + (size_t)(c0 + ql) * E + g * 8;
  const __bf16* wl0 = WTL + (size_t)(c0 + ql) * E + g * 8;

  f32x4 acc[4] = {};
#pragma unroll
  for (int k0 = 0; k0 < 8; ++k0) {
    bf16x8 a  = *(const bf16x8*)(xp + k0 * 32);
    bf16x8 al = *(const bf16x8*)(xlp + k0 * 32);
#pragma unroll
    for (int j = 0; j < 4; ++j) {
      bf16x8 bh = *(const bf16x8*)(wh0 + (size_t)j * 16 * E + k0 * 32);
      bf16x8 bl = *(const bf16x8*)(wl0 + (size_t)j * 16 * E + k0 * 32);
      acc[j] = __builtin_amdgcn_mfma_f32_16x16x32_bf16(a,  bh, acc[j], 0, 0, 0);
      acc[j] = __builtin_amdgcn_mfma_f32_16x16x32_bf16(al, bh, acc[j], 0, 0, 0);
      acc[j] = __builtin_amdgcn_mfma_f32_16x16x32_bf16(a,  bl, acc[j], 0, 0, 0);
    }
  }
#pragma unroll
  for (int j = 0; j < 4; ++j) {
    const int c = c0 + 16 * j + ql;
    const float bv = bias[c];
#pragma unroll
    for (int r = 0; r < 4; ++r) {
      const int n = r0 + g * 4 + r;
      out[(size_t)n * E + c] = acc[j][r] + bv;
    }
  }
}

// ============ no-LDS MFMA flash attention, 64q/wave (R7-proven config) ============
// grid 512 = 64 qtiles x 8 heads (h = blockIdx&7 -> per-XCD L2 K/V residency)
// block 512 = 8 waves; wave w: 64 queries x key-tiles [st, st+nt) of 32 keys
// (tiles 17/17/16x6 = 130). 4 q-frags per wave, 1-deep register prefetch.
__global__ __launch_bounds__(512, 4) void attn_kernel(
    const __bf16* __restrict__ qb, const __bf16* __restrict__ kb,
    const __bf16* __restrict__ vtp, __bf16* __restrict__ ahi, __bf16* __restrict__ alo)
{
  __shared__ float OUT[4][64][36];   // pad 36: 16B-aligned f32x4, 2-way banks max
  __shared__ float LS[4][64];

  const int t = threadIdx.x;
  const int w = t >> 6, lane = t & 63;
  const int ql = lane & 15, g = lane >> 4;
  const int b = blockIdx.x;
  const int h = b & 7, qt = b >> 3;
  const int n0 = qt * 64;

  bf16x8 bq[4];
#pragma unroll
  for (int f = 0; f < 4; ++f)
    bq[f] = *(const bf16x8*)(qb + ((size_t)h * NQ + n0 + f * 16 + ql) * HD + g * 8);

  const int st = w * 16 + (w < 2 ? w : 2);   // 0,17,34,50,66,82,98,114
  const int nt = 16 + (w < 2 ? 1 : 0);

  const __bf16* kp = kb  + ((size_t)h * NK + st * 32 + ql) * HD + g * 8;
  const __bf16* vp = vtp + ((size_t)(h * HD) + ql) * NK + st * 32 + g * 8;  // dims 0-15
  const __bf16* vq = vp + (size_t)16 * NK;                                  // dims 16-31

  f32x4 o0[4] = {}, o1[4] = {};
  float ls[4] = {0.f, 0.f, 0.f, 0.f};

  bf16x8 kf0 = *(const bf16x8*)(kp);
  bf16x8 kf1 = *(const bf16x8*)(kp + 512);
  bf16x8 vf0 = *(const bf16x8*)(vp);
  bf16x8 vf1 = *(const bf16x8*)(vq);

#define TILE(C2V)                                                                   \
  _Pragma("unroll")                                                                 \
  for (int f = 0; f < 4; ++f) {                                                     \
    f32x4 s0 = __builtin_amdgcn_mfma_f32_16x16x32_bf16(kf0, bq[f], C2V, 0, 0, 0);   \
    f32x4 s1 = __builtin_amdgcn_mfma_f32_16x16x32_bf16(kf1, bq[f], C2V, 0, 0, 0);   \
    float e0 = __builtin_amdgcn_exp2f(s0[0]), e1 = __builtin_amdgcn_exp2f(s0[1]);   \
    float e2 = __builtin_amdgcn_exp2f(s0[2]), e3 = __builtin_amdgcn_exp2f(s0[3]);   \
    float e4 = __builtin_amdgcn_exp2f(s1[0]), e5 = __builtin_amdgcn_exp2f(s1[1]);   \
    float e6 = __builtin_amdgcn_exp2f(s1[2]), e7 = __builtin_amdgcn_exp2f(s1[3]);   \
    ls[f] += ((e0 + e1) + (e2 + e3)) + ((e4 + e5) + (e6 + e7));                     \
    bf16x8 p;                                                                       \
    p[0] = (__bf16)e0; p[1] = (__bf16)e1; p[2] = (__bf16)e2; p[3] = (__bf16)e3;     \
    p[4] = (__bf16)e4; p[5] = (__bf16)e5; p[6] = (__bf16)e6; p[7] = (__bf16)e7;     \
    o0[f] = __builtin_amdgcn_mfma_f32_16x16x32_bf16(p, vf0, o0[f], 0, 0, 0);        \
    o1[f] = __builtin_amdgcn_mfma_f32_16x16x32_bf16(p, vf1, o1[f], 0, 0, 0);        \
  }

  for (int it = 0; it < nt - 1; ++it) {
    bf16x8 nk0 = *(const bf16x8*)(kp + (size_t)(it + 1) * 1024);
    bf16x8 nk1 = *(const bf16x8*)(kp + (size_t)(it + 1) * 1024 + 512);
    bf16x8 nv0 = *(const bf16x8*)(vp + (size_t)(it + 1) * 32);
    bf16x8 nv1 = *(const bf16x8*)(vq + (size_t)(it + 1) * 32);
    const float c2 = (st + it < 128) ? C2_SP : C2_PTR;
    const f32x4 c2v = {c2, c2, c2, c2};
    TILE(c2v)
    kf0 = nk0; kf1 = nk1; vf0 = nv0; vf1 = nv1;
  }
  {
    const float c2 = (st + nt - 1 < 128) ? C2_SP : C2_PTR;
    const f32x4 c2v = {c2, c2, c2, c2};
    TILE(c2v)
  }
#undef TILE

#pragma unroll
  for (int f = 0; f < 4; ++f) {
    ls[f] += __shfl_xor(ls[f], 16);
    ls[f] += __shfl_xor(ls[f], 32);
  }

  // two-phase partial merge: waves 0-3 write, waves 4-7 add
  if (w < 4) {
#pragma unroll
    for (int f = 0; f < 4; ++f) {
#pragma unroll
      for (int r = 0; r < 4; ++r) {
        OUT[w][f * 16 + g * 4 + r][ql]      = o0[f][r];
        OUT[w][f * 16 + g * 4 + r][16 + ql] = o1[f][r];
      }
      if (g == 0) LS[w][f * 16 + ql] = ls[f];
    }
  }
  __syncthreads();
  if (w >= 4) {
    const int w4 = w - 4;
#pragma unroll
    for (int f = 0; f < 4; ++f) {
#pragma unroll
      for (int r = 0; r < 4; ++r) {
        OUT[w4][f * 16 + g * 4 + r][ql]      += o0[f][r];
        OUT[w4][f * 16 + g * 4 + r][16 + ql] += o1[f][r];
      }
      if (g == 0) LS[w4][f * 16 + ql] += ls[f];
    }
  }
  __syncthreads();

  {
    const int q = t >> 3, d0 = (t & 7) * 4;
    f32x4 s = *(const f32x4*)&OUT[0][q][d0];
    float lsum = LS[0][q];
#pragma unroll
    for (int w2 = 1; w2 < 4; ++w2) {
      s += *(const f32x4*)&OUT[w2][q][d0];
      lsum += LS[w2][q];
    }
    const float inv = 1.0f / lsum;
    bf16x4 hv, lv;
#pragma unroll
    for (int i = 0; i < 4; ++i) {
      float o = s[i] * inv;
      __bf16 bh = (__bf16)o;
      hv[i] = bh;
      lv[i] = (__bf16)(o - (float)bh);
    }
    const size_t off = (size_t)(n0 + q) * E + h * HD + d0;
    *(bf16x4*)(ahi + off) = hv;
    *(bf16x4*)(alo + off) = lv;
  }
}

extern "C" void kernel_launch(void* const* d_in, const int* in_sizes, int n_in,
                              void* d_out, int out_size, void* d_ws, size_t ws_size,
                              hipStream_t stream)
{
  const float* q  = (const float*)d_in[0];
  const float* k  = (const float*)d_in[1];
  const float* v  = (const float*)d_in[2];
  const float* Wq = (const float*)d_in[3];
  const float* bq = (const float*)d_in[4];
  const float* Wk = (const float*)d_in[5];
  const float* bk = (const float*)d_in[6];
  const float* Wv = (const float*)d_in[7];
  const float* bv = (const float*)d_in[8];
  const float* Wo = (const float*)d_in[9];
  const float* bo = (const float*)d_in[10];
  float* out = (float*)d_out;

  char* wsp = (char*)d_ws;
  __bf16* wthi = (__bf16*)(wsp);               //   524,288 (4 x 256x256)
  __bf16* wtlo = (__bf16*)(wsp + 524288);      //   524,288
  __bf16* qbb  = (__bf16*)(wsp + 1048576);     // 2,097,152
  __bf16* kbb  = (__bf16*)(wsp + 3145728);     // 2,129,920
  __bf16* vtp  = (__bf16*)(wsp + 5275648);     // 2,129,920
  __bf16* ahi  = (__bf16*)(wsp + 7405568);     // 2,097,152
  __bf16* alo  = (__bf16*)(wsp + 9502720);     // 2,097,152 -> end 11,599,872

  wprep_kernel<<<256, 256, 0, stream>>>(Wq, Wk, Wv, Wo, wthi, wtlo);
  gemm_qkv<<<776, 256, 0, stream>>>(q, k, v, wthi, bq, bk, bv, qbb, kbb, vtp);
  // attn launched TWICE (idempotent): dur_us(this round) - dur_us(R7=70) = exact attn cost.
  attn_kernel<<<512, 512, 0, stream>>>(qbb, kbb, vtp, ahi, alo);
  attn_kernel<<<512, 512, 0, stream>>>(qbb, kbb, vtp, ahi, alo);
  gemm_o<<<256, 256, 0, stream>>>(ahi, alo, wthi + 3 * 65536, wtlo + 3 * 65536, bo, out);
}

// Round 11
// 72.974 us; speedup vs baseline: 3.2473x; 1.3225x over previous
//
#include <hip/hip_runtime.h>
#include <hip/hip_bf16.h>
#include <cstdint>

#define NQ 4096
#define NK 4160        // 4096 pooled spatial + 64 ptr = 130 tiles of 32
#define NSP 16384
#define E 256
#define HD 32
// Q is pre-scaled by SC2E = SCALE*log2e at projection time, so p = exp2(S + c2)
#define SC2E 0.2550348652937f
#define C2_SP  -12.426950408889634f   // (ln4 - 10) * log2e
#define C2_PTR -14.426950408889634f   // (-10) * log2e

typedef __attribute__((ext_vector_type(4))) float f32x4;
typedef __attribute__((ext_vector_type(8))) __bf16 bf16x8;
typedef __attribute__((ext_vector_type(4))) __bf16 bf16x4;

// ============ weights prep: W^T hi/lo (4 x 256x256) ============
__global__ __launch_bounds__(256) void wprep_kernel(
    const float* __restrict__ Wq, const float* __restrict__ Wk,
    const float* __restrict__ Wv, const float* __restrict__ Wo,
    __bf16* __restrict__ wthi, __bf16* __restrict__ wtlo)
{
  __shared__ float tl[32][33];
  const int b = blockIdx.x, t = threadIdx.x;
  const int wsel = b >> 6, tile = b & 63;
  const float* W = (wsel == 0) ? Wq : (wsel == 1) ? Wk : (wsel == 2) ? Wv : Wo;
  __bf16* oh = wthi + (size_t)wsel * 65536;
  __bf16* ol = wtlo + (size_t)wsel * 65536;
  const int tr = (tile >> 3) * 32, tc = (tile & 7) * 32;
  const int rr = t >> 3, cc = (t & 7) * 4;
  *(float4*)&tl[rr][cc] = *(const float4*)(W + (size_t)(tr + rr) * E + tc + cc);
  __syncthreads();
  bf16x4 hv, lv;
#pragma unroll
  for (int i = 0; i < 4; ++i) {
    float x = tl[cc + i][rr];           // W[tr+cc+i][tc+rr]
    __bf16 bh = (__bf16)x;
    hv[i] = bh;
    lv[i] = (__bf16)(x - (float)bh);
  }
  *(bf16x4*)(oh + (size_t)(tc + rr) * E + tr + cc) = hv;
  *(bf16x4*)(ol + (size_t)(tc + rr) * E + tr + cc) = lv;
}

// ============ fused stage(+pool)+MFMA projection: 16 rows x 256 cols per block ============
// MODE 0: Q (f32 in) -> bf16 [h][n][32], scaled by SC2E
// MODE 1: K (f32 in, pooled) -> bf16 [h][n][32]
// MODE 2: V (f32 in, pooled) -> bf16 V^T permuted [h*32+d][NK] (swapped operands)
template<int MODE>
__device__ __forceinline__ void qkv_body(
    const float* __restrict__ Xsrc, const __bf16* __restrict__ WTH,
    const float* __restrict__ bias, void* __restrict__ Y, int r0)
{
  __shared__ __bf16 Xs[16][264];   // pad 264: <=2-way banks on b128 frag reads
  const int t = threadIdx.x;

  // ---- stage: pool (K/V) or copy (Q), f32 -> bf16, into LDS ----
  {
    const int pr = t >> 4, f4 = t & 15;   // pooled row, float4-chunk
    const int p = r0 + pr;
    float4 x[4];
    if (MODE == 0) {
      const float* src = Xsrc + (size_t)p * E + f4 * 4;
#pragma unroll
      for (int j = 0; j < 4; ++j) x[j] = *(const float4*)(src + j * 64);
    } else if (p < 4096) {
      const int fr = p >> 10, hp = (p >> 5) & 31, wp = p & 31;
      const float* src = Xsrc + (size_t)(fr * 4096 + hp * 128 + wp * 2) * E + f4 * 4;
#pragma unroll
      for (int j = 0; j < 4; ++j) {
        float4 a = *(const float4*)(src + j * 64);
        float4 b = *(const float4*)(src + j * 64 + E);
        float4 c = *(const float4*)(src + j * 64 + 64 * E);
        float4 d = *(const float4*)(src + j * 64 + 65 * E);
        x[j].x = 0.25f * (a.x + b.x + c.x + d.x);
        x[j].y = 0.25f * (a.y + b.y + c.y + d.y);
        x[j].z = 0.25f * (a.z + b.z + c.z + d.z);
        x[j].w = 0.25f * (a.w + b.w + c.w + d.w);
      }
    } else {
      const float* src = Xsrc + (size_t)(NSP + p - 4096) * E + f4 * 4;
#pragma unroll
      for (int j = 0; j < 4; ++j) x[j] = *(const float4*)(src + j * 64);
    }
#pragma unroll
    for (int j = 0; j < 4; ++j) {
      bf16x4 o;
      o[0] = (__bf16)x[j].x; o[1] = (__bf16)x[j].y;
      o[2] = (__bf16)x[j].z; o[3] = (__bf16)x[j].w;
      *(bf16x4*)&Xs[pr][f4 * 4 + j * 64] = o;
    }
  }
  __syncthreads();

  // ---- compute ----
  const int lane = t & 63, ql = lane & 15, g = lane >> 4;
  const int w = t >> 6, c0 = w * 64;
  const __bf16* wh0 = WTH + (size_t)(c0 + ql) * E + g * 8;

  f32x4 acc[4] = {};
#pragma unroll
  for (int k0 = 0; k0 < 8; ++k0) {
    bf16x8 a = *(const bf16x8*)&Xs[ql][g * 8 + k0 * 32];
#pragma unroll
    for (int j = 0; j < 4; ++j) {
      bf16x8 bh = *(const bf16x8*)(wh0 + (size_t)j * 16 * E + k0 * 32);
      if (MODE == 2) acc[j] = __builtin_amdgcn_mfma_f32_16x16x32_bf16(bh, a, acc[j], 0, 0, 0);
      else           acc[j] = __builtin_amdgcn_mfma_f32_16x16x32_bf16(a, bh, acc[j], 0, 0, 0);
    }
  }

  if (MODE == 0 || MODE == 1) {
    const int NN = (MODE == 0) ? NQ : NK;
#pragma unroll
    for (int j = 0; j < 4; ++j) {
      const int c = c0 + 16 * j + ql;
      const float bv = bias[c];
      const int hh = c >> 5, d = c & 31;
      __bf16* dst = (__bf16*)Y + (size_t)hh * NN * HD + d;
#pragma unroll
      for (int r = 0; r < 4; ++r) {
        const int n = r0 + g * 4 + r;
        float o = acc[j][r] + bv;
        if (MODE == 0) o *= SC2E;
        dst[(size_t)n * HD] = (__bf16)o;
      }
    }
  } else {
    const int n = r0 + ql;
    const int wi = n & 31;
    const int pos = ((wi & 15) >> 2) * 8 + (wi & 3) + 4 * ((wi >> 4) & 1);
    const size_t nb = (size_t)(n >> 5) * 32 + pos;
#pragma unroll
    for (int j = 0; j < 4; ++j)
#pragma unroll
      for (int r = 0; r < 4; ++r) {
        const int ch = c0 + 16 * j + g * 4 + r;
        const int hh = ch >> 5, d = ch & 31;
        ((__bf16*)Y)[(size_t)(hh * HD + d) * NK + nb] = (__bf16)(acc[j][r] + bias[ch]);
      }
  }
}

// fused Q/K/V projection: blocks [0,256) Q, [256,516) K, [516,776) V
__global__ __launch_bounds__(256) void gemm_qkv(
    const float* __restrict__ q, const float* __restrict__ k, const float* __restrict__ v,
    const __bf16* __restrict__ wthi,
    const float* __restrict__ bq, const float* __restrict__ bk, const float* __restrict__ bv,
    __bf16* __restrict__ qb, __bf16* __restrict__ kb, __bf16* __restrict__ vtp)
{
  const int b = blockIdx.x;
  if (b < 256) {
    qkv_body<0>(q, wthi, bq, qb, b * 16);
  } else if (b < 516) {
    qkv_body<1>(k, wthi + 65536, bk, kb, (b - 256) * 16);
  } else {
    qkv_body<2>(v, wthi + 2 * 65536, bv, vtp, (b - 516) * 16);
  }
}

// ============ O-GEMM: out = [ahi+alo](N,256) @ Wo(256,256) + bo, 3-mfma hi/lo ============
__global__ __launch_bounds__(256) void gemm_o(
    const __bf16* __restrict__ ahi, const __bf16* __restrict__ alo,
    const __bf16* __restrict__ WTH, const __bf16* __restrict__ WTL,
    const float* __restrict__ bias, float* __restrict__ out)
{
  const int r0 = blockIdx.x * 16;
  const int t = threadIdx.x;
  const int lane = t & 63, ql = lane & 15, g = lane >> 4;
  const int w = t >> 6, c0 = w * 64;

  const __bf16* xp  = ahi + (size_t)(r0 + ql) * E + g * 8;
  const __bf16* xlp = alo + (size_t)(r0 + ql) * E + g * 8;
  const __bf16* wh0 = WTH + (size_t)(c0 + ql) * E + g * 8;
  const __bf16* wl0 = WTL + (size_t)(c0 + ql) * E + g * 8;

  f32x4 acc[4] = {};
#pragma unroll
  for (int k0 = 0; k0 < 8; ++k0) {
    bf16x8 a  = *(const bf16x8*)(xp + k0 * 32);
    bf16x8 al = *(const bf16x8*)(xlp + k0 * 32);
#pragma unroll
    for (int j = 0; j < 4; ++j) {
      bf16x8 bh = *(const bf16x8*)(wh0 + (size_t)j * 16 * E + k0 * 32);
      bf16x8 bl = *(const bf16x8*)(wl0 + (size_t)j * 16 * E + k0 * 32);
      acc[j] = __builtin_amdgcn_mfma_f32_16x16x32_bf16(a,  bh, acc[j], 0, 0, 0);
      acc[j] = __builtin_amdgcn_mfma_f32_16x16x32_bf16(al, bh, acc[j], 0, 0, 0);
      acc[j] = __builtin_amdgcn_mfma_f32_16x16x32_bf16(a,  bl, acc[j], 0, 0, 0);
    }
  }
#pragma unroll
  for (int j = 0; j < 4; ++j) {
    const int c = c0 + 16 * j + ql;
    const float bv = bias[c];
#pragma unroll
    for (int r = 0; r < 4; ++r) {
      const int n = r0 + g * 4 + r;
      out[(size_t)n * E + c] = acc[j][r] + bv;
    }
  }
}

// ============ no-LDS MFMA flash attention, 64q/wave, 16-way ksplit ============
// grid 512 = 64 qtiles x 8 heads (h = blockIdx&7 -> per-XCD L2 K/V residency)
// block 1024 = 16 waves; wave w: 64 queries x key-tiles [st, st+nt) of 32 keys
// (tiles 9/9/8x14 = 130). 4 q-frags per wave, 1-deep register prefetch (R7 body).
// launch_bounds(1024, 2): cap 256 VGPR — allocator FREE (R9's min-8 pin forced
// VGPR=32 -> catastrophic spill). R7-identical body settles at 64 VGPR; at 64
// VGPR + 75.8KB LDS, 2 blocks/CU co-reside -> 32 waves/CU (2x R7's TLP).
__global__ __launch_bounds__(1024, 2) void attn_kernel(
    const __bf16* __restrict__ qb, const __bf16* __restrict__ kb,
    const __bf16* __restrict__ vtp, __bf16* __restrict__ ahi, __bf16* __restrict__ alo)
{
  __shared__ float OUT[8][64][36];   // pad 36: 16B-aligned f32x4, 2-way banks max
  __shared__ float LS[8][64];

  const int t = threadIdx.x;
  const int w = t >> 6, lane = t & 63;
  const int ql = lane & 15, g = lane >> 4;
  const int b = blockIdx.x;
  const int h = b & 7, qt = b >> 3;
  const int n0 = qt * 64;

  bf16x8 bq[4];
#pragma unroll
  for (int f = 0; f < 4; ++f)
    bq[f] = *(const bf16x8*)(qb + ((size_t)h * NQ + n0 + f * 16 + ql) * HD + g * 8);

  const int st = w * 8 + (w < 2 ? w : 2);   // 0,9,18,26,...,122
  const int nt = 8 + (w < 2 ? 1 : 0);       // 9,9,8x14 -> 130

  const __bf16* kp = kb  + ((size_t)h * NK + st * 32 + ql) * HD + g * 8;
  const __bf16* vp = vtp + ((size_t)(h * HD) + ql) * NK + st * 32 + g * 8;  // dims 0-15
  const __bf16* vq = vp + (size_t)16 * NK;                                  // dims 16-31

  f32x4 o0[4] = {}, o1[4] = {};
  float ls[4] = {0.f, 0.f, 0.f, 0.f};

  bf16x8 kf0 = *(const bf16x8*)(kp);
  bf16x8 kf1 = *(const bf16x8*)(kp + 512);
  bf16x8 vf0 = *(const bf16x8*)(vp);
  bf16x8 vf1 = *(const bf16x8*)(vq);

#define TILE(C2V)                                                                   \
  _Pragma("unroll")                                                                 \
  for (int f = 0; f < 4; ++f) {                                                     \
    f32x4 s0 = __builtin_amdgcn_mfma_f32_16x16x32_bf16(kf0, bq[f], C2V, 0, 0, 0);   \
    f32x4 s1 = __builtin_amdgcn_mfma_f32_16x16x32_bf16(kf1, bq[f], C2V, 0, 0, 0);   \
    float e0 = __builtin_amdgcn_exp2f(s0[0]), e1 = __builtin_amdgcn_exp2f(s0[1]);   \
    float e2 = __builtin_amdgcn_exp2f(s0[2]), e3 = __builtin_amdgcn_exp2f(s0[3]);   \
    float e4 = __builtin_amdgcn_exp2f(s1[0]), e5 = __builtin_amdgcn_exp2f(s1[1]);   \
    float e6 = __builtin_amdgcn_exp2f(s1[2]), e7 = __builtin_amdgcn_exp2f(s1[3]);   \
    ls[f] += ((e0 + e1) + (e2 + e3)) + ((e4 + e5) + (e6 + e7));                     \
    bf16x8 p;                                                                       \
    p[0] = (__bf16)e0; p[1] = (__bf16)e1; p[2] = (__bf16)e2; p[3] = (__bf16)e3;     \
    p[4] = (__bf16)e4; p[5] = (__bf16)e5; p[6] = (__bf16)e6; p[7] = (__bf16)e7;     \
    o0[f] = __builtin_amdgcn_mfma_f32_16x16x32_bf16(p, vf0, o0[f], 0, 0, 0);        \
    o1[f] = __builtin_amdgcn_mfma_f32_16x16x32_bf16(p, vf1, o1[f], 0, 0, 0);        \
  }

  for (int it = 0; it < nt - 1; ++it) {
    bf16x8 nk0 = *(const bf16x8*)(kp + (size_t)(it + 1) * 1024);
    bf16x8 nk1 = *(const bf16x8*)(kp + (size_t)(it + 1) * 1024 + 512);
    bf16x8 nv0 = *(const bf16x8*)(vp + (size_t)(it + 1) * 32);
    bf16x8 nv1 = *(const bf16x8*)(vq + (size_t)(it + 1) * 32);
    const float c2 = (st + it < 128) ? C2_SP : C2_PTR;
    const f32x4 c2v = {c2, c2, c2, c2};
    TILE(c2v)
    kf0 = nk0; kf1 = nk1; vf0 = nv0; vf1 = nv1;
  }
  {
    const float c2 = (st + nt - 1 < 128) ? C2_SP : C2_PTR;
    const f32x4 c2v = {c2, c2, c2, c2};
    TILE(c2v)
  }
#undef TILE

#pragma unroll
  for (int f = 0; f < 4; ++f) {
    ls[f] += __shfl_xor(ls[f], 16);
    ls[f] += __shfl_xor(ls[f], 32);
  }

  // two-phase partial merge: waves 0-7 write, waves 8-15 add
  if (w < 8) {
#pragma unroll
    for (int f = 0; f < 4; ++f) {
#pragma unroll
      for (int r = 0; r < 4; ++r) {
        OUT[w][f * 16 + g * 4 + r][ql]      = o0[f][r];
        OUT[w][f * 16 + g * 4 + r][16 + ql] = o1[f][r];
      }
      if (g == 0) LS[w][f * 16 + ql] = ls[f];
    }
  }
  __syncthreads();
  if (w >= 8) {
    const int w8 = w - 8;
#pragma unroll
    for (int f = 0; f < 4; ++f) {
#pragma unroll
      for (int r = 0; r < 4; ++r) {
        OUT[w8][f * 16 + g * 4 + r][ql]      += o0[f][r];
        OUT[w8][f * 16 + g * 4 + r][16 + ql] += o1[f][r];
      }
      if (g == 0) LS[w8][f * 16 + ql] += ls[f];
    }
  }
  __syncthreads();

  if (t < 512) {
    const int q = t >> 3, d0 = (t & 7) * 4;
    f32x4 s = *(const f32x4*)&OUT[0][q][d0];
    float lsum = LS[0][q];
#pragma unroll
    for (int w2 = 1; w2 < 8; ++w2) {
      s += *(const f32x4*)&OUT[w2][q][d0];
      lsum += LS[w2][q];
    }
    const float inv = 1.0f / lsum;
    bf16x4 hv, lv;
#pragma unroll
    for (int i = 0; i < 4; ++i) {
      float o = s[i] * inv;
      __bf16 bh = (__bf16)o;
      hv[i] = bh;
      lv[i] = (__bf16)(o - (float)bh);
    }
    const size_t off = (size_t)(n0 + q) * E + h * HD + d0;
    *(bf16x4*)(ahi + off) = hv;
    *(bf16x4*)(alo + off) = lv;
  }
}

extern "C" void kernel_launch(void* const* d_in, const int* in_sizes, int n_in,
                              void* d_out, int out_size, void* d_ws, size_t ws_size,
                              hipStream_t stream)
{
  const float* q  = (const float*)d_in[0];
  const float* k  = (const float*)d_in[1];
  const float* v  = (const float*)d_in[2];
  const float* Wq = (const float*)d_in[3];
  const float* bq = (const float*)d_in[4];
  const float* Wk = (const float*)d_in[5];
  const float* bk = (const float*)d_in[6];
  const float* Wv = (const float*)d_in[7];
  const float* bv = (const float*)d_in[8];
  const float* Wo = (const float*)d_in[9];
  const float* bo = (const float*)d_in[10];
  float* out = (float*)d_out;

  char* wsp = (char*)d_ws;
  __bf16* wthi = (__bf16*)(wsp);               //   524,288 (4 x 256x256)
  __bf16* wtlo = (__bf16*)(wsp + 524288);      //   524,288
  __bf16* qbb  = (__bf16*)(wsp + 1048576);     // 2,097,152
  __bf16* kbb  = (__bf16*)(wsp + 3145728);     // 2,129,920
  __bf16* vtp  = (__bf16*)(wsp + 5275648);     // 2,129,920
  __bf16* ahi  = (__bf16*)(wsp + 7405568);     // 2,097,152
  __bf16* alo  = (__bf16*)(wsp + 9502720);     // 2,097,152 -> end 11,599,872

  wprep_kernel<<<256, 256, 0, stream>>>(Wq, Wk, Wv, Wo, wthi, wtlo);
  gemm_qkv<<<776, 256, 0, stream>>>(q, k, v, wthi, bq, bk, bv, qbb, kbb, vtp);
  attn_kernel<<<512, 1024, 0, stream>>>(qbb, kbb, vtp, ahi, alo);
  gemm_o<<<256, 256, 0, stream>>>(ahi, alo, wthi + 3 * 65536, wtlo + 3 * 65536, bo, out);
}